// Round 1
// baseline (680.274 us; speedup 1.0000x reference)
//
#include <hip/hip_runtime.h>

#define NPTS   262144
#define CHUNK  256          // points per block
#define BLOCK  1024         // threads per block
#define NG     36           // F*2*3 encodings
#define NC     16           // features
#define RES    32           // grid resolution
#define TAB_FLOATS (NG * NC * RES)   // 18432 floats = 72 KB

// out[p, c*36 + g] = lerp(table[g][c][:], iy(val)) + val
//   g = f*6 + s*3 + d ; val = (s? cos : sin)(point[p][d] * 2^f)
//   iy = (val+1)*15.5 ; i0 = floor(iy) ; w = iy - i0 ; v1 read at i0+1
//   (i0==31 only when iy==31.0 exactly -> w==0, so unclamped i0+1 read is
//    masked by w; one pad float after the table keeps the last read finite)

__global__ __launch_bounds__(BLOCK) void freqhash_kernel(
    const float* __restrict__ points,
    const float* __restrict__ features,
    float* __restrict__ out)
{
    __shared__ float tab[TAB_FLOATS + 4];   // [g][c][i], i contiguous (matches global layout)
    __shared__ float sval[CHUNK * NG];      // per-point encoded values

    const int t = threadIdx.x;
    const int chunk_base = blockIdx.x * CHUNK;

    // ---- stage tables: features global layout (g,c,res,1) == [g][c][i] ----
    {
        const float4* __restrict__ src = (const float4*)features;
        float4* dst = (float4*)tab;
        #pragma unroll
        for (int i = 0; i < TAB_FLOATS / 4 / BLOCK + 1; ++i) {
            int idx = t + i * BLOCK;
            if (idx < TAB_FLOATS / 4) dst[idx] = src[idx];
        }
        if (t == 0) {
            tab[TAB_FLOATS + 0] = 0.f; tab[TAB_FLOATS + 1] = 0.f;
            tab[TAB_FLOATS + 2] = 0.f; tab[TAB_FLOATS + 3] = 0.f;
        }
    }

    // ---- phase 1: per-point encodings (all 64 lanes doing transcendentals) ----
    {
        const int phat    = t >> 2;        // point within chunk: 0..255
        const int quarter = t & 3;         // which 9 of the 36 g's
        const int p = chunk_base + phat;
        const float x = points[p * 3 + 0];
        const float y = points[p * 3 + 1];
        const float z = points[p * 3 + 2];
        #pragma unroll
        for (int k = 0; k < 9; ++k) {
            const int g   = quarter * 9 + k;
            const int f   = g / 6;
            const int rem = g - f * 6;
            const int s   = rem / 3;           // 0 = sin, 1 = cos
            const int d   = rem - s * 3;
            const float coord = (d == 0) ? x : ((d == 1) ? y : z);
            const float freq  = (float)(1 << f);      // exactly 2**linspace(0,5,6)
            const float rev   = coord * freq * 0.15915494309189535f; // x/(2*pi)
            const float r     = __builtin_amdgcn_fractf(rev);        // v_fract
            const float sv    = __builtin_amdgcn_sinf(r);            // v_sin (revolutions)
            const float cv    = __builtin_amdgcn_cosf(r);            // v_cos
            const float val   = s ? cv : sv;
            sval[t * 9 + k] = val;   // == (t>>2)*36 + (t&3)*9 + k  (stride 9 -> conflict-free)
        }
    }
    __syncthreads();

    // ---- phase 2: 144 float4 outputs per point, lanes -> consecutive float4 ----
    // float4 q covers out[j..j+3], j = 4*(q%144) = c*36 + g0 (never crosses c: 36%4==0)
    float* __restrict__ outp = out + (size_t)chunk_base * (NC * NG);
    #pragma unroll 2
    for (int it = 0; it < (CHUNK * NC * NG / 4) / BLOCK; ++it) {   // 36 iters
        const unsigned q    = (unsigned)t + (unsigned)it * BLOCK;  // 0..36863
        const unsigned phat = q / 144u;
        const unsigned rq   = q - phat * 144u;
        const unsigned c    = rq / 9u;
        const unsigned g0   = (rq - c * 9u) * 4u;                  // 0,4,...,32

        const float4 v4 = *(const float4*)&sval[phat * NG + g0];   // 16B aligned
        const int base = (int)(g0 * NC + c) * RES;                 // element offset of [g0][c][0]

        float res[4];
        const float vv[4] = { v4.x, v4.y, v4.z, v4.w };
        #pragma unroll
        for (int k = 0; k < 4; ++k) {
            const float val = vv[k];
            const float iy  = __builtin_fmaf(val, 15.5f, 15.5f);   // (val+1)*0.5*(res-1)
            const float fl  = floorf(iy);
            const float w   = iy - fl;
            int i0 = (int)fl;
            i0 = i0 < 0 ? 0 : (i0 > 31 ? 31 : i0);
            const float* __restrict__ row = &tab[base + k * (NC * RES) + i0];
            const float v0 = row[0];
            const float v1 = row[1];            // ds_read2_b32 with v0
            res[k] = __builtin_fmaf(w, v1 - v0, v0) + val;
        }
        *(float4*)&outp[(size_t)q * 4] = make_float4(res[0], res[1], res[2], res[3]);
    }
}

extern "C" void kernel_launch(void* const* d_in, const int* in_sizes, int n_in,
                              void* d_out, int out_size, void* d_ws, size_t ws_size,
                              hipStream_t stream) {
    const float* points   = (const float*)d_in[0];
    // d_in[1] (freqs) is exactly [1,2,4,8,16,32]; computed in-kernel as (float)(1<<f)
    const float* features = (const float*)d_in[2];
    float* out = (float*)d_out;
    freqhash_kernel<<<dim3(NPTS / CHUNK), dim3(BLOCK), 0, stream>>>(points, features, out);
}

// Round 2
// 656.123 us; speedup vs baseline: 1.0368x; 1.0368x over previous
//
#include <hip/hip_runtime.h>

#define NPTS   262144
#define NG     36            // F*2*3 encodings, g = f*6 + s*3 + d
#define NC     16
#define RES    32
#define NROWS  (NG * NC)     // 576 table rows
#define PADR   33            // padded row length: bank = (16g + c + i0) % 32
#define TABF   (NROWS * PADR)// 19008 floats = 76,032 B -> 2 blocks/CU

#define K1_BLOCK 256
#define K2_BLOCK 1024
#define K2_GRID  512                       // exactly 2 blocks/CU
#define TOTAL_Q  (NPTS * 144)              // 37,748,736 float4 outputs
#define K2_ITERS (TOTAL_Q / (K2_BLOCK * K2_GRID))   // 72, exact

// ---------------- K1: positional encode, 1 thread per point ----------------
__global__ __launch_bounds__(K1_BLOCK) void encode_kernel(
    const float* __restrict__ points, float* __restrict__ sval)
{
    const int p = blockIdx.x * K1_BLOCK + threadIdx.x;
    const float x = points[p * 3 + 0];
    const float y = points[p * 3 + 1];
    const float z = points[p * 3 + 2];
    float v[NG];
    #pragma unroll
    for (int f = 0; f < 6; ++f) {
        const float w = (float)(1 << f) * 0.15915494309189535f;  // 2^f / (2*pi)
        #pragma unroll
        for (int d = 0; d < 3; ++d) {
            const float coord = (d == 0) ? x : ((d == 1) ? y : z);
            const float r = __builtin_amdgcn_fractf(coord * w);  // v_fract
            v[f * 6 + d]     = __builtin_amdgcn_sinf(r);         // v_sin (revolutions)
            v[f * 6 + 3 + d] = __builtin_amdgcn_cosf(r);         // v_cos
        }
    }
    float4* __restrict__ dst = (float4*)(sval + (size_t)p * NG); // 144 B/point, 16B-aligned
    #pragma unroll
    for (int j = 0; j < 9; ++j) dst[j] = ((const float4*)v)[j];
}

// ------------- K2: LDS-table lerp + residual, store-BW-bound ---------------
// out[p, c*36 + g] = lerp(tab[g][c][:], (val+1)*15.5) + val
// float4 q covers out[4q..4q+3]: phat=q/144, rq=q%144, c=rq/9, g0=4*(rq%9)
__global__ __launch_bounds__(K2_BLOCK, 8) void gather_kernel(
    const float* __restrict__ features,
    const float* __restrict__ sval,
    float* __restrict__ out)
{
    __shared__ float tab[TABF];   // [g][c][33]; pad slot zeroed (w==0 tap reads it)
    for (int idx = threadIdx.x; idx < TABF; idx += K2_BLOCK) {
        const int row = idx / PADR;
        const int col = idx - row * PADR;
        tab[idx] = (col < RES) ? features[row * RES + col] : 0.f;
    }
    __syncthreads();

    const unsigned tid = blockIdx.x * K2_BLOCK + threadIdx.x;
    const unsigned T   = K2_BLOCK * K2_GRID;
    float4* __restrict__ out4 = (float4*)out;

    #pragma unroll 2
    for (int it = 0; it < K2_ITERS; ++it) {
        const unsigned q    = tid + (unsigned)it * T;
        const unsigned phat = q / 144u;
        const unsigned rq   = q - phat * 144u;
        const unsigned c    = rq / 9u;
        const unsigned m    = rq - c * 9u;               // g-quad index 0..8
        const float4 v4 = *(const float4*)&sval[phat * 36u + m * 4u]; // coalesced, L1-hot
        const int base  = (int)((m * 4u * NC + c) * PADR);

        float res[4];
        const float vv[4] = { v4.x, v4.y, v4.z, v4.w };
        #pragma unroll
        for (int k = 0; k < 4; ++k) {
            const float val = vv[k];
            const float iy  = __builtin_fmaf(val, 15.5f, 15.5f);  // in [0, 31]
            int i0 = (int)iy;                                     // trunc == floor (iy >= 0)
            i0 = i0 < 0 ? 0 : (i0 > RES - 1 ? RES - 1 : i0);
            const float w = iy - (float)i0;
            const float* __restrict__ row = &tab[base + k * (NC * PADR) + i0];
            const float v0 = row[0];
            const float v1 = row[1];                              // ds_read2_b32 pair
            res[k] = __builtin_fmaf(w, v1 - v0, v0) + val;
        }
        out4[q] = make_float4(res[0], res[1], res[2], res[3]);
    }
}

extern "C" void kernel_launch(void* const* d_in, const int* in_sizes, int n_in,
                              void* d_out, int out_size, void* d_ws, size_t ws_size,
                              hipStream_t stream) {
    const float* points   = (const float*)d_in[0];
    // d_in[1] (freqs) is exactly [1,2,4,8,16,32]; computed in-kernel as (float)(1<<f)
    const float* features = (const float*)d_in[2];
    float* out  = (float*)d_out;
    float* sval = (float*)d_ws;   // 37.7 MB scratch (ws is ~2.4 GB per poison-fill size)

    encode_kernel<<<dim3(NPTS / K1_BLOCK), dim3(K1_BLOCK), 0, stream>>>(points, sval);
    gather_kernel<<<dim3(K2_GRID), dim3(K2_BLOCK), 0, stream>>>(features, sval, out);
}

// Round 4
// 624.151 us; speedup vs baseline: 1.0899x; 1.0512x over previous
//
#include <hip/hip_runtime.h>

#define NPTS   262144
#define NG     36            // F*2*3 encodings, g = f*6 + s*3 + d
#define NC     16
#define RES    32
#define NROWS  (NG * NC)     // 576 table rows
#define PADR   33            // padded row: bank = (row + i0) % 32; col 32 zeroed
#define TABF   (NROWS * PADR)// 19008 floats = 76,032 B -> 2 blocks/CU (152 KB)

#define K1_BLOCK 256
#define K2_BLOCK 576         // = 4*144 = 9 waves: rq = tid%144 is loop-invariant
#define K2_GRID  512         // 512 points/block, exactly 2 blocks per CU
#define PTS_PER_BLOCK 512
#define K2_ITERS 128         // 4 points per iteration

typedef float v4f __attribute__((ext_vector_type(4)));   // native vec for nt builtins

// ---------------- K1: positional encode, 1 thread per point ----------------
__global__ __launch_bounds__(K1_BLOCK) void encode_kernel(
    const float* __restrict__ points, float* __restrict__ sval)
{
    const int p = blockIdx.x * K1_BLOCK + threadIdx.x;
    const float x = points[p * 3 + 0];
    const float y = points[p * 3 + 1];
    const float z = points[p * 3 + 2];
    float v[NG];
    #pragma unroll
    for (int f = 0; f < 6; ++f) {
        const float w = (float)(1 << f) * 0.15915494309189535f;  // 2^f / (2*pi)
        #pragma unroll
        for (int d = 0; d < 3; ++d) {
            const float coord = (d == 0) ? x : ((d == 1) ? y : z);
            const float r = __builtin_amdgcn_fractf(coord * w);  // v_fract
            v[f * 6 + d]     = __builtin_amdgcn_sinf(r);         // v_sin (revolutions)
            v[f * 6 + 3 + d] = __builtin_amdgcn_cosf(r);         // v_cos
        }
    }
    v4f* __restrict__ dst = (v4f*)(sval + (size_t)p * NG);
    #pragma unroll
    for (int j = 0; j < 9; ++j) dst[j] = ((const v4f*)v)[j];
}

// ------------- K2: LDS-table lerp + residual, store-BW-bound ---------------
// out[p, c*36 + g] = lerp(tab[g][c][:], (val+1)*15.5) + val
// float4 q covers out[4q..4q+3]: phat=q/144, rq=q%144, c=rq/9, g0=4*(rq%9).
// Block owns contiguous q range [b*73728, +73728): rq == tid%144, hoisted.
__global__ __launch_bounds__(K2_BLOCK, 5) void gather_kernel(
    const float* __restrict__ features,
    const float* __restrict__ sval,
    float* __restrict__ out)
{
    __shared__ float tab[TABF];   // [g][c][33]; pad col zeroed (iy==31 tap, w==0)
    for (int idx = threadIdx.x; idx < TABF; idx += K2_BLOCK) {
        const int row = idx / PADR;
        const int col = idx - row * PADR;
        tab[idx] = (col < RES) ? features[row * RES + col] : 0.f;
    }
    __syncthreads();

    const int tid = threadIdx.x;
    const int rq  = tid % 144;                 // loop-invariant quad id within point
    const int c   = rq / 9;
    const int m   = rq - c * 9;                // g-quad 0..8 -> g0 = 4*m
    const int tb0 = (m * 4 * NC + c) * PADR;   // tab element base for k=0

    const int phat0 = blockIdx.x * PTS_PER_BLOCK + tid / 144;
    const v4f* __restrict__ sv = (const v4f*)sval + (size_t)phat0 * 9 + m;
    v4f* __restrict__ o = (v4f*)out + (size_t)blockIdx.x * (PTS_PER_BLOCK * 144) + tid;

    #pragma unroll 2
    for (int it = 0; it < K2_ITERS; ++it) {    // 4 points per iteration
        const v4f v4 = sv[it * 36];            // phat advances by 4 -> 36 float4s
        v4f res;
        #pragma unroll
        for (int k = 0; k < 4; ++k) {
            const float val = v4[k];
            const float iy  = __builtin_fmaf(val, 15.5f, 15.5f);  // in [0, 31]
            const int   i0  = (int)iy;                            // trunc == floor
            const float w   = iy - (float)i0;
            const float* __restrict__ row = &tab[tb0 + k * (NC * PADR) + i0];
            const float v0 = row[0];
            const float v1 = row[1];                              // ds_read2_b32 pair
            res[k] = __builtin_fmaf(w, v1 - v0, v0) + val;
        }
        __builtin_nontemporal_store(res, &o[it * K2_BLOCK]);      // keep L2 for sval
    }
}

extern "C" void kernel_launch(void* const* d_in, const int* in_sizes, int n_in,
                              void* d_out, int out_size, void* d_ws, size_t ws_size,
                              hipStream_t stream) {
    const float* points   = (const float*)d_in[0];
    // d_in[1] (freqs) is exactly [1,2,4,8,16,32]; computed in-kernel as (float)(1<<f)
    const float* features = (const float*)d_in[2];
    float* out  = (float*)d_out;
    float* sval = (float*)d_ws;   // 37.7 MB scratch

    encode_kernel<<<dim3(NPTS / K1_BLOCK), dim3(K1_BLOCK), 0, stream>>>(points, sval);
    gather_kernel<<<dim3(K2_GRID), dim3(K2_BLOCK), 0, stream>>>(features, sval, out);
}